// Round 4
// baseline (134.783 us; speedup 1.0000x reference)
//
#include <hip/hip_runtime.h>
#include <hip/hip_bf16.h>
#include <cstdint>

// MultiHeadAttention_76338748719257 — MI355X (gfx950). R4.
// attn v4: 2-wave blocks (QBLK=64, grid 1024 = 4 blocks/CU), shifted-PV pipeline:
//   per barrier section: stage K(kt+1),V(kt) | QK^T(kt) MFMA | PV(kt-1) MFMA
//   (independent, P in regs) | softmax(kt) VALU. permlane32_swap for cross-half
//   reductions; s_setprio around MFMA cluster. GEMMs unchanged from R3.

typedef __bf16 bf16_t;
typedef bf16_t bf16x8 __attribute__((ext_vector_type(8)));
typedef bf16_t bf16x4 __attribute__((ext_vector_type(4)));
typedef float  f32x4  __attribute__((ext_vector_type(4)));
typedef float  f32x16 __attribute__((ext_vector_type(16)));
typedef unsigned int u32;
typedef u32 u32x2 __attribute__((ext_vector_type(2)));

#define MFMA16(a, b, c) __builtin_amdgcn_mfma_f32_16x16x32_bf16((a), (b), (c), 0, 0, 0)
#define MFMA32(a, b, c) __builtin_amdgcn_mfma_f32_32x32x16_bf16((a), (b), (c), 0, 0, 0)

#define GLOAD_LDS16(gptr, lptr)                                                      \
  __builtin_amdgcn_global_load_lds(                                                  \
      (const __attribute__((address_space(1))) void*)(gptr),                         \
      (__attribute__((address_space(3))) void*)(lptr), 16, 0, 0)

namespace {
constexpr int kS = 2048, kE = 1024, kD = 64;
constexpr int kM = 4096;
constexpr float kQScale = 0.03125f;      // 1/sqrt(E), folded into Q projection
constexpr float kL2E = 1.44269504088896f;
}

__device__ inline u32 pkbf(float a, float b) {
  u32 r;
  asm("v_cvt_pk_bf16_f32 %0, %1, %2" : "=v"(r) : "v"(a), "v"(b));
  return r;
}

__device__ inline bf16x8 make_pfrag(float v0, float v1, float v2, float v3,
                                    float v4, float v5, float v6, float v7) {
  u32 A0 = pkbf(v0, v1), A1 = pkbf(v2, v3);
  u32 B0 = pkbf(v4, v5), B1 = pkbf(v6, v7);
  u32x2 r0 = __builtin_amdgcn_permlane32_swap(A0, B0, false, false);
  u32x2 r1 = __builtin_amdgcn_permlane32_swap(A1, B1, false, false);
  union { u32 w[4]; bf16x8 v; } u;
  u.w[0] = r0[0]; u.w[1] = r1[0]; u.w[2] = r0[1]; u.w[3] = r1[1];
  return u.v;
}

// cross-half (lane^32) combine without LDS
__device__ inline float xhalf_max(float x) {
  u32 xu = __builtin_bit_cast(u32, x);
  u32x2 r = __builtin_amdgcn_permlane32_swap(xu, xu, false, false);
  return fmaxf(__builtin_bit_cast(float, r[0]), __builtin_bit_cast(float, r[1]));
}
__device__ inline float xhalf_sum(float x) {
  u32 xu = __builtin_bit_cast(u32, x);
  u32x2 r = __builtin_amdgcn_permlane32_swap(xu, xu, false, false);
  return __builtin_bit_cast(float, r[0]) + __builtin_bit_cast(float, r[1]);
}

// ---------------- fp32 -> bf16 convert (4 buffers per launch) ----------------
__global__ void cvt_batch(const float* __restrict__ s0, const float* __restrict__ s1,
                          const float* __restrict__ s2, const float* __restrict__ s3,
                          bf16_t* __restrict__ d0, bf16_t* __restrict__ d1,
                          bf16_t* __restrict__ d2, bf16_t* __restrict__ d3, int n4) {
  const float* s; bf16_t* d;
  switch (blockIdx.y) {
    case 0:  s = s0; d = d0; break;
    case 1:  s = s1; d = d1; break;
    case 2:  s = s2; d = d2; break;
    default: s = s3; d = d3; break;
  }
  int stride = gridDim.x * blockDim.x;
  for (int i = blockIdx.x * blockDim.x + threadIdx.x; i < n4; i += stride) {
    float4 v = reinterpret_cast<const float4*>(s)[i];
    bf16x4 o;
    o[0] = (bf16_t)v.x; o[1] = (bf16_t)v.y; o[2] = (bf16_t)v.z; o[3] = (bf16_t)v.w;
    reinterpret_cast<bf16x4*>(d)[i] = o;
  }
}

// ---------------- fused QKV projection GEMM (unchanged from R3) ----------------
__global__ __launch_bounds__(256, 2)
void gemm_qkv(const bf16_t* __restrict__ qb, const bf16_t* __restrict__ kb,
              const bf16_t* __restrict__ vb, const bf16_t* __restrict__ W,
              const float* __restrict__ bq, const float* __restrict__ bk,
              const float* __restrict__ bv,
              bf16_t* __restrict__ Qp, bf16_t* __restrict__ Kp, bf16_t* __restrict__ Vp) {
  constexpr int K = kE, BK = 64;
  __shared__ __align__(16) bf16_t As[128 * BK];
  __shared__ __align__(16) bf16_t Bs[128 * BK];
  const int tid = threadIdx.x, lane = tid & 63, wave = tid >> 6;
  const int fr = lane & 15, fg = lane >> 4;
  const int region = blockIdx.x >> 3;
  const int bm = blockIdx.y * 128, bn = blockIdx.x * 128;
  const int bnl = (blockIdx.x & 7) * 128;
  const bf16_t* A = region == 0 ? qb : region == 1 ? kb : vb;
  const float* bias = region == 0 ? bq : region == 1 ? bk : bv;
  bf16_t* Cp = region == 0 ? Qp : region == 1 ? Kp : Vp;
  const float scale = region == 0 ? kQScale : 1.0f;
  const int wr = (wave >> 1) * 64, wc = (wave & 1) * 64;
  f32x4 acc[4][4] = {};
  for (int k0 = 0; k0 < K; k0 += BK) {
#pragma unroll
    for (int c = 0; c < 4; ++c) {
      int lin = c * 256 + tid, row = lin >> 3, ch = lin & 7, sch = ch ^ (row & 7);
      GLOAD_LDS16(A + (size_t)(bm + row) * K + k0 + sch * 8, (char*)As + lin * 16);
    }
#pragma unroll
    for (int c = 0; c < 4; ++c) {
      int lin = c * 256 + tid, row = lin >> 3, ch = lin & 7, sch = ch ^ (row & 7);
      GLOAD_LDS16(W + (size_t)(bn + row) * K + k0 + sch * 8, (char*)Bs + lin * 16);
    }
    __syncthreads();
#pragma unroll
    for (int kk = 0; kk < 2; ++kk) {
      bf16x8 af[4], bfv[4];
#pragma unroll
      for (int i = 0; i < 4; ++i) {
        int row = wr + i * 16 + fr;
        int ch = (kk * 4 + fg) ^ (row & 7);
        af[i] = *reinterpret_cast<const bf16x8*>((const char*)As + row * 128 + ch * 16);
      }
#pragma unroll
      for (int j = 0; j < 4; ++j) {
        int row = wc + j * 16 + fr;
        int ch = (kk * 4 + fg) ^ (row & 7);
        bfv[j] = *reinterpret_cast<const bf16x8*>((const char*)Bs + row * 128 + ch * 16);
      }
#pragma unroll
      for (int i = 0; i < 4; ++i)
#pragma unroll
        for (int j = 0; j < 4; ++j)
          acc[i][j] = MFMA16(af[i], bfv[j], acc[i][j]);
    }
    __syncthreads();
  }
#pragma unroll
  for (int i = 0; i < 4; ++i)
#pragma unroll
    for (int j = 0; j < 4; ++j) {
      int coll = bnl + wc + j * 16 + fr;
      float bvv = bias[coll];
#pragma unroll
      for (int r = 0; r < 4; ++r) {
        int row = bm + wr + i * 16 + fg * 4 + r;
        Cp[(size_t)row * kE + coll] = (bf16_t)((acc[i][j][r] + bvv) * scale);
      }
    }
}

// ---------------- final GEMM (unchanged from R3) ----------------
__global__ __launch_bounds__(256, 2)
void gemm_out(const bf16_t* __restrict__ A, const bf16_t* __restrict__ Bm,
              const float* __restrict__ bias, float* __restrict__ Cout) {
  constexpr int K = kE, BK = 64;
  __shared__ __align__(16) bf16_t As[128 * BK];
  __shared__ __align__(16) bf16_t Bs[64 * BK];
  const int tid = threadIdx.x, lane = tid & 63, wave = tid >> 6;
  const int fr = lane & 15, fg = lane >> 4;
  const int bm = blockIdx.y * 128, bn = blockIdx.x * 64;
  const int wr = wave * 32;
  f32x4 acc[2][4] = {};
  for (int k0 = 0; k0 < K; k0 += BK) {
#pragma unroll
    for (int c = 0; c < 4; ++c) {
      int lin = c * 256 + tid, row = lin >> 3, ch = lin & 7, sch = ch ^ (row & 7);
      GLOAD_LDS16(A + (size_t)(bm + row) * K + k0 + sch * 8, (char*)As + lin * 16);
    }
#pragma unroll
    for (int c = 0; c < 2; ++c) {
      int lin = c * 256 + tid, row = lin >> 3, ch = lin & 7, sch = ch ^ (row & 7);
      GLOAD_LDS16(Bm + (size_t)(bn + row) * K + k0 + sch * 8, (char*)Bs + lin * 16);
    }
    __syncthreads();
#pragma unroll
    for (int kk = 0; kk < 2; ++kk) {
      bf16x8 af[2], bfv[4];
#pragma unroll
      for (int i = 0; i < 2; ++i) {
        int row = wr + i * 16 + fr;
        int ch = (kk * 4 + fg) ^ (row & 7);
        af[i] = *reinterpret_cast<const bf16x8*>((const char*)As + row * 128 + ch * 16);
      }
#pragma unroll
      for (int j = 0; j < 4; ++j) {
        int row = j * 16 + fr;
        int ch = (kk * 4 + fg) ^ (row & 7);
        bfv[j] = *reinterpret_cast<const bf16x8*>((const char*)Bs + row * 128 + ch * 16);
      }
#pragma unroll
      for (int i = 0; i < 2; ++i)
#pragma unroll
        for (int j = 0; j < 4; ++j)
          acc[i][j] = MFMA16(af[i], bfv[j], acc[i][j]);
    }
    __syncthreads();
  }
#pragma unroll
  for (int i = 0; i < 2; ++i)
#pragma unroll
    for (int j = 0; j < 4; ++j) {
      int col = bn + j * 16 + fr;
      float bvv = bias[col];
#pragma unroll
      for (int r = 0; r < 4; ++r) {
        int row = bm + wr + i * 16 + fg * 4 + r;
        Cout[(size_t)row * kE + col] = acc[i][j][r] + bvv;
      }
    }
}

// ---------------- per-head V transpose (unchanged from R3) ----------------
__global__ __launch_bounds__(256)
void vtranspose(const bf16_t* __restrict__ Vp, bf16_t* __restrict__ VpT) {
  __shared__ __align__(16) bf16_t T[256 * 64];
  const int tid = threadIdx.x;
  const size_t hb = (size_t)blockIdx.y * (kS * kD);
  const bf16_t* src = Vp + hb + (size_t)blockIdx.x * 256 * kD;
  bf16_t* dst = VpT + hb + blockIdx.x * 256;
#pragma unroll
  for (int c = 0; c < 8; ++c) {
    int lin = c * 256 + tid;
    int row = lin >> 3, ch = lin & 7;
    bf16x8 v = *reinterpret_cast<const bf16x8*>(src + row * kD + ch * 8);
    *reinterpret_cast<bf16x8*>((char*)T + row * 128 + ((ch ^ ((row >> 3) & 7)) * 16)) = v;
  }
  __syncthreads();
#pragma unroll
  for (int c = 0; c < 8; ++c) {
    int lin = c * 256 + tid;
    int d = lin >> 5, kc = lin & 31;
    bf16x8 o;
#pragma unroll
    for (int e = 0; e < 8; ++e) {
      int s = kc * 8 + e;
      o[e] = *reinterpret_cast<const bf16_t*>(
          (const char*)T + s * 128 + (((d >> 3) ^ ((s >> 3) & 7)) * 16) + (d & 7) * 2);
    }
    *reinterpret_cast<bf16x8*>(dst + (size_t)d * kS + kc * 8) = o;
  }
}

// ---------------- flash attention v4 ----------------
// LDS layout: Kb0 @0, Kb1 @8192, Vb0 @16384, Vb1 @24576 (each 8KB = 64x64 bf16).
// Body(kt): sync | stage K(kt+1)->Kb[(kt+1)&1], V(kt)->Vb[kt&1] | QK(kt) from
// Kb[kt&1] | PV(kt-1) from Vb[(kt-1)&1] with PFR | softmax(kt) -> PFW.
#define ATTN_BODY(KT, PFW, PFR, DOPV, STAGEK)                                        \
  {                                                                                  \
    __syncthreads();                                                                 \
    const int cb = ((KT) & 1) * 8192;                                                \
    const int vbR = 16384 + ((((KT) + 1) & 1) * 8192);                               \
    if (STAGEK) {                                                                    \
      const bf16_t* Ktp = Kp + hbase + (size_t)((KT) + 1) * 64 * kD;                 \
      const int nb = (((KT) + 1) & 1) * 8192;                                        \
      _Pragma("unroll")                                                              \
      for (int c = 0; c < 4; ++c) {                                                  \
        int lin = c * 128 + tid, row = lin >> 3, ch = lin & 7, sch = ch ^ (row & 7); \
        GLOAD_LDS16(Ktp + row * kD + sch * 8, smem + nb + lin * 16);                 \
      }                                                                              \
    }                                                                                \
    {                                                                                \
      const bf16_t* Vtp = VpT + hbase + (KT) * 64;                                   \
      const int vbW = 16384 + (((KT) & 1) * 8192);                                   \
      _Pragma("unroll")                                                              \
      for (int c = 0; c < 4; ++c) {                                                  \
        int lin = c * 128 + tid, row = lin >> 3, ch = lin & 7, sch = ch ^ (row & 7); \
        GLOAD_LDS16(Vtp + (size_t)row * kS + sch * 8, smem + vbW + lin * 16);        \
      }                                                                              \
    }                                                                                \
    f32x16 s0 = {}, s1 = {};                                                         \
    __builtin_amdgcn_s_setprio(1);                                                   \
    _Pragma("unroll")                                                                \
    for (int ct = 0; ct < 4; ++ct) {                                                 \
      bf16x8 k0 = *reinterpret_cast<const bf16x8*>(                                  \
          smem + cb + ql * 128 + (((2 * ct + hi) ^ (ql & 7)) * 16));                 \
      bf16x8 k1 = *reinterpret_cast<const bf16x8*>(                                  \
          smem + cb + (32 + ql) * 128 + (((2 * ct + hi) ^ (ql & 7)) * 16));          \
      s0 = MFMA32(k0, qf[ct], s0);                                                   \
      s1 = MFMA32(k1, qf[ct], s1);                                                   \
    }                                                                                \
    if (DOPV) {                                                                      \
      _Pragma("unroll")                                                              \
      for (int ks = 0; ks < 4; ++ks) {                                               \
        bf16x8 v0 = *reinterpret_cast<const bf16x8*>(                                \
            smem + vbR + ql * 128 + (((2 * ks + hi) ^ (ql & 7)) * 16));              \
        bf16x8 v1 = *reinterpret_cast<const bf16x8*>(                                \
            smem + vbR + (32 + ql) * 128 + (((2 * ks + hi) ^ (ql & 7)) * 16));       \
        o0 = MFMA32(v0, PFR[ks], o0);                                                \
        o1 = MFMA32(v1, PFR[ks], o1);                                                \
      }                                                                              \
    }                                                                                \
    __builtin_amdgcn_s_setprio(0);                                                   \
    float t0 = -3.0e38f, t1 = -3.0e38f, t2 = -3.0e38f, t3 = -3.0e38f;                \
    _Pragma("unroll")                                                                \
    for (int r = 0; r < 16; r += 4) {                                                \
      t0 = fmaxf(t0, fmaxf(s0[r], s0[r + 1]));                                       \
      t1 = fmaxf(t1, fmaxf(s0[r + 2], s0[r + 3]));                                   \
      t2 = fmaxf(t2, fmaxf(s1[r], s1[r + 1]));                                       \
      t3 = fmaxf(t3, fmaxf(s1[r + 2], s1[r + 3]));                                   \
    }                                                                                \
    float tm = fmaxf(fmaxf(t0, t1), fmaxf(t2, t3));                                  \
    tm = xhalf_max(tm);                                                              \
    if (!__all(tm <= m + 8.0f)) {                                                    \
      float mn = fmaxf(m, tm);                                                       \
      float rs = __builtin_amdgcn_exp2f((m - mn) * kL2E);                            \
      m = mn; Lp *= rs;                                                              \
      _Pragma("unroll")                                                              \
      for (int r = 0; r < 16; ++r) { o0[r] *= rs; o1[r] *= rs; }                     \
    }                                                                                \
    const float ml = m * kL2E;                                                       \
    float a0 = 0.f, a1 = 0.f;                                                        \
    _Pragma("unroll")                                                                \
    for (int r = 0; r < 16; ++r) {                                                   \
      s0[r] = __builtin_amdgcn_exp2f(__builtin_fmaf(s0[r], kL2E, -ml));              \
      s1[r] = __builtin_amdgcn_exp2f(__builtin_fmaf(s1[r], kL2E, -ml));              \
      a0 += s0[r]; a1 += s1[r];                                                      \
    }                                                                                \
    Lp += a0 + a1;                                                                   \
    PFW[0] = make_pfrag(s0[0], s0[1], s0[2], s0[3], s0[4], s0[5], s0[6], s0[7]);     \
    PFW[1] = make_pfrag(s0[8], s0[9], s0[10], s0[11], s0[12], s0[13], s0[14], s0[15]);\
    PFW[2] = make_pfrag(s1[0], s1[1], s1[2], s1[3], s1[4], s1[5], s1[6], s1[7]);     \
    PFW[3] = make_pfrag(s1[8], s1[9], s1[10], s1[11], s1[12], s1[13], s1[14], s1[15]);\
  }

__global__ __launch_bounds__(128, 2)
void attn_fwd(const bf16_t* __restrict__ Qp, const bf16_t* __restrict__ Kp,
              const bf16_t* __restrict__ VpT, bf16_t* __restrict__ Op) {
  __shared__ __align__(16) char smem[32768];
  const int tid = threadIdx.x, lane = tid & 63, wave = tid >> 6;
  const int ql = lane & 31, hi = lane >> 5;
  // XCD swizzle: 1024 blocks, 128 consecutive per XCD (4 whole heads)
  const int newb = ((int)blockIdx.x & 7) * 128 + ((int)blockIdx.x >> 3);
  const int head = newb >> 5, qt = newb & 31;
  const size_t hbase = (size_t)head * (kS * kD);
  const int q0 = qt * 64 + wave * 32;

  bf16x8 qf[4];
#pragma unroll
  for (int ct = 0; ct < 4; ++ct)
    qf[ct] = *reinterpret_cast<const bf16x8*>(
        Qp + hbase + (size_t)(q0 + ql) * kD + ct * 16 + hi * 8);

  float m = -3.0e38f, Lp = 0.0f;
  f32x16 o0 = {}, o1 = {};
  bf16x8 pfA[4], pfB[4];

  // prologue: stage K(0) -> Kb0
  {
    const bf16_t* Ktp = Kp + hbase;
#pragma unroll
    for (int c = 0; c < 4; ++c) {
      int lin = c * 128 + tid, row = lin >> 3, ch = lin & 7, sch = ch ^ (row & 7);
      GLOAD_LDS16(Ktp + row * kD + sch * 8, smem + lin * 16);
    }
  }

  ATTN_BODY(0, pfA, pfB, false, true)
#pragma unroll 1
  for (int it = 0; it < 15; ++it) {
    const int kt = 1 + 2 * it;
    ATTN_BODY(kt, pfB, pfA, true, true)
    ATTN_BODY(kt + 1, pfA, pfB, true, true)
  }
  ATTN_BODY(31, pfB, pfA, true, false)

  // tail: PV(31) from Vb1 with pfB
  __syncthreads();
#pragma unroll
  for (int ks = 0; ks < 4; ++ks) {
    bf16x8 v0 = *reinterpret_cast<const bf16x8*>(
        smem + 24576 + ql * 128 + (((2 * ks + hi) ^ (ql & 7)) * 16));
    bf16x8 v1 = *reinterpret_cast<const bf16x8*>(
        smem + 24576 + (32 + ql) * 128 + (((2 * ks + hi) ^ (ql & 7)) * 16));
    o0 = MFMA32(v0, pfB[ks], o0);
    o1 = MFMA32(v1, pfB[ks], o1);
  }

  // epilogue: normalize, transpose via LDS (own 4KB region in dead Kb0), store
  float L = xhalf_sum(Lp);
  float inv = 1.0f / L;
#pragma unroll
  for (int r = 0; r < 16; ++r) { o0[r] *= inv; o1[r] *= inv; }
  const int wb = wave * 4096;
#pragma unroll
  for (int c = 0; c < 4; ++c) {
    {
      u32 w0 = pkbf(o0[4 * c + 0], o0[4 * c + 1]);
      u32 w1 = pkbf(o0[4 * c + 2], o0[4 * c + 3]);
      int d0 = 8 * c + 4 * hi;
      int byte = (wb + ql * 128 + d0 * 2) ^ ((ql & 7) << 4);
      *reinterpret_cast<u32x2*>(smem + byte) = (u32x2){w0, w1};
    }
    {
      u32 w0 = pkbf(o1[4 * c + 0], o1[4 * c + 1]);
      u32 w1 = pkbf(o1[4 * c + 2], o1[4 * c + 3]);
      int d0 = 32 + 8 * c + 4 * hi;
      int byte = (wb + ql * 128 + d0 * 2) ^ ((ql & 7) << 4);
      *reinterpret_cast<u32x2*>(smem + byte) = (u32x2){w0, w1};
    }
  }
  asm volatile("s_waitcnt lgkmcnt(0)" ::: "memory");
  __builtin_amdgcn_sched_barrier(0);
#pragma unroll
  for (int it = 0; it < 4; ++it) {
    int lin = it * 64 + lane;
    int qr = lin >> 3, ch = lin & 7;
    int byte = wb + qr * 128 + ((ch * 16) ^ ((qr & 7) << 4));
    bf16x8 vrow = *reinterpret_cast<const bf16x8*>(smem + byte);
    *reinterpret_cast<bf16x8*>(Op + hbase + (size_t)(q0 + qr) * kD + ch * 8) = vrow;
  }
}

// ---------------- host launch ----------------
extern "C" void kernel_launch(void* const* d_in, const int* in_sizes, int n_in,
                              void* d_out, int out_size, void* d_ws, size_t ws_size,
                              hipStream_t stream) {
  (void)in_sizes; (void)n_in; (void)out_size; (void)ws_size;
  const float* q  = (const float*)d_in[0];
  const float* k  = (const float*)d_in[1];
  const float* v  = (const float*)d_in[2];
  const float* wq = (const float*)d_in[3];
  const float* bq = (const float*)d_in[4];
  const float* wk = (const float*)d_in[5];
  const float* bk = (const float*)d_in[6];
  const float* wv = (const float*)d_in[7];
  const float* bv = (const float*)d_in[8];
  const float* wo = (const float*)d_in[9];
  const float* bo = (const float*)d_in[10];
  float* out = (float*)d_out;

  char* ws = (char*)d_ws;
  const size_t MB = 1ull << 20;
  bf16_t* qb   = (bf16_t*)(ws +  0 * MB);
  bf16_t* kb   = (bf16_t*)(ws +  8 * MB);
  bf16_t* vb   = (bf16_t*)(ws + 16 * MB);
  bf16_t* wqkv = (bf16_t*)(ws + 24 * MB);
  bf16_t* wob  = (bf16_t*)(ws + 30 * MB);
  bf16_t* Qp   = (bf16_t*)(ws + 32 * MB);
  bf16_t* Kp   = (bf16_t*)(ws + 40 * MB);
  bf16_t* Vp   = (bf16_t*)(ws + 48 * MB);
  bf16_t* Opb  = (bf16_t*)(ws + 56 * MB);
  bf16_t* VpT  = (bf16_t*)(ws +  0 * MB);  // reuses qb (dead after projection)

  const int nQKV4 = (kM * kE) / 4;
  const int nW4 = (kE * kE) / 4;
  cvt_batch<<<dim3(512, 3), 256, 0, stream>>>(q, k, v, v, qb, kb, vb, vb, nQKV4);
  cvt_batch<<<dim3(128, 4), 256, 0, stream>>>(wq, wk, wv, wo, wqkv, wqkv + 1048576,
                                              wqkv + 2097152, wob, nW4);

  gemm_qkv<<<dim3(24, 32), 256, 0, stream>>>(qb, kb, vb, wqkv, bq, bk, bv, Qp, Kp, Vp);

  vtranspose<<<dim3(kS / 256, 32), 256, 0, stream>>>(Vp, VpT);

  attn_fwd<<<dim3(1024), 128, 0, stream>>>(Qp, Kp, VpT, Opb);

  gemm_out<<<dim3(16, 32), 256, 0, stream>>>(Opb, wob, bo, out);
}